// Round 1
// baseline (533.819 us; speedup 1.0000x reference)
//
#include <hip/hip_runtime.h>
#include <hip/hip_cooperative_groups.h>

namespace cg = cooperative_groups;

#define NBINS   256
#define B       64
#define NPB     786432          // 3*512*512 elements per batch
#define NF4     (NPB / 4)       // 196608 float4 per batch
#define BPB     16              // blocks per batch
#define THREADS 256
#define GRID    (B * BPB)       // 1024 blocks = 4/CU on 256 CUs

// ws layout: pb   [GRID]  float2   per-block {min,max} partials (8 KB)
//            bhist[B*NBINS] u32    per-batch histograms (64 KB)

// ---------------- phase 1: per-block min/max (+ zero bhist) ----------------
__device__ __forceinline__ void phase_minmax(const float4* __restrict__ x,
                                             float2* __restrict__ pb,
                                             unsigned* __restrict__ bhist) {
    // fold k_init in: first B blocks zero the per-batch histograms
    if (blockIdx.x < B) bhist[blockIdx.x * NBINS + threadIdx.x] = 0u;

    const int batch = blockIdx.x / BPB;
    const int blk   = blockIdx.x % BPB;
    const float4* p = x + (size_t)batch * NF4;

    float mn = 3.402823466e38f, mx = -3.402823466e38f;
    int t = blk * THREADS + threadIdx.x;
    // NF4 / (BPB*THREADS) = 48 exact, no tail
    #pragma unroll 4
    for (int i = t; i < NF4; i += BPB * THREADS) {
        float4 v = p[i];
        mn = fminf(mn, fminf(fminf(v.x, v.y), fminf(v.z, v.w)));
        mx = fmaxf(mx, fmaxf(fmaxf(v.x, v.y), fmaxf(v.z, v.w)));
    }
    for (int o = 32; o > 0; o >>= 1) {
        mn = fminf(mn, __shfl_down(mn, o));
        mx = fmaxf(mx, __shfl_down(mx, o));
    }
    __shared__ float smn[4], smx[4];
    int wid = threadIdx.x >> 6;
    if ((threadIdx.x & 63) == 0) { smn[wid] = mn; smx[wid] = mx; }
    __syncthreads();
    if (threadIdx.x == 0) {
        mn = fminf(fminf(smn[0], smn[1]), fminf(smn[2], smn[3]));
        mx = fmaxf(fmaxf(smx[0], smx[1]), fmaxf(smx[2], smx[3]));
        pb[blockIdx.x] = make_float2(mn, mx);   // no atomics, no init needed
    }
}

// ---------------- phase 2: histogram (LDS replicas, then global add) -------
__device__ __forceinline__ void phase_hist(const float4* __restrict__ x,
                                           const float2* __restrict__ pb,
                                           unsigned* __restrict__ bhist) {
    const int batch = blockIdx.x / BPB;
    const int blk   = blockIdx.x % BPB;

    // reduce this batch's 16 per-block partials (uniform, scalar-friendly)
    float mn = 3.402823466e38f, mx = -3.402823466e38f;
    #pragma unroll
    for (int j = 0; j < BPB; ++j) {
        float2 v = pb[batch * BPB + j];
        mn = fminf(mn, v.x);
        mx = fmaxf(mx, v.y);
    }
    // Match reference exactly: rng/lo selection, f32 divide then multiply,
    // truncating int cast, clip [0, 255].
    const float rng   = (mx > mn) ? (mx - mn) : 2.0f;
    const float lo    = (mx > mn) ? mn : (mn - 1.0f);
    const float scale = (float)NBINS / rng;

    // 4 per-wave replicas to cut LDS-atomic contention
    __shared__ unsigned lh[4][NBINS];
    for (int i = threadIdx.x; i < 4 * NBINS; i += THREADS)
        ((unsigned*)lh)[i] = 0u;
    __syncthreads();

    unsigned* h = lh[threadIdx.x >> 6];
    const float4* p = x + (size_t)batch * NF4;
    int t = blk * THREADS + threadIdx.x;
    for (int i = t; i < NF4; i += BPB * THREADS) {
        float4 v = p[i];
        int i0 = (int)((v.x - lo) * scale);
        int i1 = (int)((v.y - lo) * scale);
        int i2 = (int)((v.z - lo) * scale);
        int i3 = (int)((v.w - lo) * scale);
        i0 = min(max(i0, 0), NBINS - 1);
        i1 = min(max(i1, 0), NBINS - 1);
        i2 = min(max(i2, 0), NBINS - 1);
        i3 = min(max(i3, 0), NBINS - 1);
        atomicAdd(&h[i0], 1u);
        atomicAdd(&h[i1], 1u);
        atomicAdd(&h[i2], 1u);
        atomicAdd(&h[i3], 1u);
    }
    __syncthreads();

    unsigned* gh = bhist + batch * NBINS;
    for (int i = threadIdx.x; i < NBINS; i += THREADS) {
        unsigned s = lh[0][i] + lh[1][i] + lh[2][i] + lh[3][i];
        if (s) atomicAdd(&gh[i], s);
    }
}

// ---------------- phase 3: entropy (single block) --------------------------
__device__ __forceinline__ void phase_entropy(const unsigned* __restrict__ bhist,
                                              float* __restrict__ out) {
    // Every element lands in exactly one bin (clip), so per-batch sum == NPB.
    const float invN = 1.0f / (float)NPB;
    float sum = 0.0f;
    for (int b = 0; b < B; ++b) {
        unsigned c = bhist[b * NBINS + threadIdx.x];
        if (c) {
            float pv = (float)c * invN;
            sum += pv * log2f(pv);
        }
    }
    for (int o = 32; o > 0; o >>= 1) sum += __shfl_down(sum, o);
    __shared__ float s[4];
    int wid = threadIdx.x >> 6;
    if ((threadIdx.x & 63) == 0) s[wid] = sum;
    __syncthreads();
    if (threadIdx.x == 0)
        out[0] = -(s[0] + s[1] + s[2] + s[3]) / (float)B;
}

// ---------------- fused cooperative kernel ---------------------------------
__global__ __launch_bounds__(THREADS, 4) void k_fused(const float4* __restrict__ x,
                                                      float2* __restrict__ pb,
                                                      unsigned* __restrict__ bhist,
                                                      float* __restrict__ out) {
    cg::grid_group g = cg::this_grid();
    phase_minmax(x, pb, bhist);
    g.sync();
    phase_hist(x, pb, bhist);
    g.sync();
    if (blockIdx.x == 0) phase_entropy(bhist, out);
}

// ---------------- non-cooperative fallback path ----------------------------
__global__ __launch_bounds__(THREADS) void k_p1(const float4* __restrict__ x,
                                                float2* __restrict__ pb,
                                                unsigned* __restrict__ bhist) {
    phase_minmax(x, pb, bhist);
}
__global__ __launch_bounds__(THREADS) void k_p2(const float4* __restrict__ x,
                                                const float2* __restrict__ pb,
                                                unsigned* __restrict__ bhist) {
    phase_hist(x, pb, bhist);
}
__global__ __launch_bounds__(THREADS) void k_p3(const unsigned* __restrict__ bhist,
                                                float* __restrict__ out) {
    phase_entropy(bhist, out);
}

extern "C" void kernel_launch(void* const* d_in, const int* in_sizes, int n_in,
                              void* d_out, int out_size, void* d_ws, size_t ws_size,
                              hipStream_t stream) {
    const float4* x = (const float4*)d_in[0];
    float* out      = (float*)d_out;
    float2* pb      = (float2*)d_ws;                                  // 8 KB
    unsigned* bhist = (unsigned*)((char*)d_ws + GRID * sizeof(float2)); // 64 KB

    static int coop = -1;
    if (coop < 0) {
        int v = 0;
        hipDeviceGetAttribute(&v, hipDeviceAttributeCooperativeLaunch, 0);
        coop = v;
    }

    bool launched = false;
    if (coop) {
        void* args[] = { (void*)&x, (void*)&pb, (void*)&bhist, (void*)&out };
        hipError_t err = hipLaunchCooperativeKernel((void*)k_fused, dim3(GRID),
                                                    dim3(THREADS), args, 0, stream);
        launched = (err == hipSuccess);
    }
    if (!launched) {
        hipLaunchKernelGGL(k_p1, dim3(GRID), dim3(THREADS), 0, stream, x, pb, bhist);
        hipLaunchKernelGGL(k_p2, dim3(GRID), dim3(THREADS), 0, stream, x, pb, bhist);
        hipLaunchKernelGGL(k_p3, dim3(1), dim3(THREADS), 0, stream, bhist, out);
    }
}

// Round 2
// 307.175 us; speedup vs baseline: 1.7378x; 1.7378x over previous
//
#include <hip/hip_runtime.h>

#define NBINS   256
#define B       64
#define NPB     786432          // 3*512*512 elements per batch
#define NF4     (NPB / 4)       // 196608 float4 per batch
#define BPB     32              // blocks per batch
#define THREADS 256
#define GRID    (B * BPB)       // 2048 blocks = 8/CU on 256 CUs

// ws layout: pb   [GRID]    float2  per-block {min,max} partials (16 KB)
//            hist [B*NBINS] u32     per-batch histograms (64 KB)

// ---------------- kernel 1: per-block min/max (+ zero hist) ----------------
__global__ __launch_bounds__(THREADS) void k_minmax(const float4* __restrict__ x,
                                                    float2* __restrict__ pb,
                                                    unsigned* __restrict__ hist) {
    // fold init in: first B blocks zero the per-batch histograms (no atomics
    // are used for min/max, so pb needs no init at all)
    if (blockIdx.x < B) hist[blockIdx.x * NBINS + threadIdx.x] = 0u;

    const int batch = blockIdx.x / BPB;
    const int blk   = blockIdx.x % BPB;
    const float4* p = x + (size_t)batch * NF4;

    float mn = 3.402823466e38f, mx = -3.402823466e38f;
    int t = blk * THREADS + threadIdx.x;
    // NF4 / (BPB*THREADS) = 24 exact, no tail
    #pragma unroll 4
    for (int i = t; i < NF4; i += BPB * THREADS) {
        float4 v = p[i];
        mn = fminf(mn, fminf(fminf(v.x, v.y), fminf(v.z, v.w)));
        mx = fmaxf(mx, fmaxf(fmaxf(v.x, v.y), fmaxf(v.z, v.w)));
    }
    // wave64 reduce
    for (int o = 32; o > 0; o >>= 1) {
        mn = fminf(mn, __shfl_down(mn, o));
        mx = fmaxf(mx, __shfl_down(mx, o));
    }
    __shared__ float smn[4], smx[4];
    int wid = threadIdx.x >> 6;
    if ((threadIdx.x & 63) == 0) { smn[wid] = mn; smx[wid] = mx; }
    __syncthreads();
    if (threadIdx.x == 0) {
        mn = fminf(fminf(smn[0], smn[1]), fminf(smn[2], smn[3]));
        mx = fmaxf(fmaxf(smx[0], smx[1]), fmaxf(smx[2], smx[3]));
        pb[blockIdx.x] = make_float2(mn, mx);   // plain store, no atomics
    }
}

// ---------------- kernel 2: histogram (LDS replicas, then global add) ------
__global__ __launch_bounds__(THREADS) void k_hist(const float4* __restrict__ x,
                                                  const float2* __restrict__ pb,
                                                  unsigned* __restrict__ hist) {
    const int batch = blockIdx.x / BPB;
    const int blk   = blockIdx.x % BPB;

    // reduce this batch's BPB per-block partials (uniform across the block,
    // broadcast-friendly scalar loads from L2)
    float mn = 3.402823466e38f, mx = -3.402823466e38f;
    #pragma unroll
    for (int j = 0; j < BPB; ++j) {
        float2 v = pb[batch * BPB + j];
        mn = fminf(mn, v.x);
        mx = fmaxf(mx, v.y);
    }
    // Match reference exactly: rng/lo selection, f32 divide then multiply,
    // truncating int cast, clip [0, 255].
    const float rng   = (mx > mn) ? (mx - mn) : 2.0f;
    const float lo    = (mx > mn) ? mn : (mn - 1.0f);
    const float scale = (float)NBINS / rng;

    // 4 per-wave replicas to keep LDS-atomic conflicts intra-wave only
    __shared__ unsigned lh[4][NBINS];
    for (int i = threadIdx.x; i < 4 * NBINS; i += THREADS)
        ((unsigned*)lh)[i] = 0u;
    __syncthreads();

    unsigned* h = lh[threadIdx.x >> 6];
    const float4* p = x + (size_t)batch * NF4;
    int t = blk * THREADS + threadIdx.x;
    for (int i = t; i < NF4; i += BPB * THREADS) {
        float4 v = p[i];
        int i0 = (int)((v.x - lo) * scale);
        int i1 = (int)((v.y - lo) * scale);
        int i2 = (int)((v.z - lo) * scale);
        int i3 = (int)((v.w - lo) * scale);
        i0 = min(max(i0, 0), NBINS - 1);
        i1 = min(max(i1, 0), NBINS - 1);
        i2 = min(max(i2, 0), NBINS - 1);
        i3 = min(max(i3, 0), NBINS - 1);
        atomicAdd(&h[i0], 1u);
        atomicAdd(&h[i1], 1u);
        atomicAdd(&h[i2], 1u);
        atomicAdd(&h[i3], 1u);
    }
    __syncthreads();

    unsigned* gh = hist + batch * NBINS;
    for (int i = threadIdx.x; i < NBINS; i += THREADS) {
        unsigned s = lh[0][i] + lh[1][i] + lh[2][i] + lh[3][i];
        if (s) atomicAdd(&gh[i], s);
    }
}

// ---------------- kernel 3: entropy (single block; exact round-0 order) ----
__global__ __launch_bounds__(THREADS) void k_entropy(const unsigned* __restrict__ hist,
                                                     float* __restrict__ out) {
    // Every element lands in exactly one bin (clip), so per-batch sum == NPB.
    // Summation order identical to the absmax==0.0 version: per thread (= per
    // bin) sequential over b with ONE accumulator, then the same 4-wave tree.
    // #pragma unroll only hoists loads (ILP); single-accumulator add order is
    // preserved, so the result stays bitwise identical.
    const float invN = 1.0f / (float)NPB;
    float sum = 0.0f;
    #pragma unroll 8
    for (int b = 0; b < B; ++b) {
        unsigned c = hist[b * NBINS + threadIdx.x];
        if (c) {
            float pv = (float)c * invN;
            sum += pv * log2f(pv);
        }
    }
    for (int o = 32; o > 0; o >>= 1) sum += __shfl_down(sum, o);
    __shared__ float s[4];
    int wid = threadIdx.x >> 6;
    if ((threadIdx.x & 63) == 0) s[wid] = sum;
    __syncthreads();
    if (threadIdx.x == 0)
        out[0] = -(s[0] + s[1] + s[2] + s[3]) / (float)B;
}

extern "C" void kernel_launch(void* const* d_in, const int* in_sizes, int n_in,
                              void* d_out, int out_size, void* d_ws, size_t ws_size,
                              hipStream_t stream) {
    const float4* x = (const float4*)d_in[0];
    float* out      = (float*)d_out;
    float2* pb      = (float2*)d_ws;                                    // 16 KB
    unsigned* hist  = (unsigned*)((char*)d_ws + GRID * sizeof(float2)); // 64 KB

    hipLaunchKernelGGL(k_minmax, dim3(GRID), dim3(THREADS), 0, stream,
                       x, pb, hist);
    hipLaunchKernelGGL(k_hist, dim3(GRID), dim3(THREADS), 0, stream,
                       x, pb, hist);
    hipLaunchKernelGGL(k_entropy, dim3(1), dim3(THREADS), 0, stream,
                       hist, out);
}